// Round 10
// baseline (893.680 us; speedup 1.0000x reference)
//
#include <hip/hip_runtime.h>

// ---------------------------------------------------------------------------
// 2-layer GCN forward, pull-mode, bf16 tables, MFMA GEMMs.
//
// R10: XCD-affine column-sliced gathers.  Gather tables stored as 8 column
// slices (gather1: 16 cols = 3.2 MB/slice, gather2: 8 cols = 1.6 MB/slice);
// gather grid = 8 * node-groups with slice = blockIdx & 7.  Round-robin
// block->XCD dispatch pins each slice to one XCD, whose 4 MiB L2 holds the
// whole slice -> random gather becomes L2-resident (R8/R9 evidence: FETCH
// is insensitive to table size while per-XCD working set > 4 MiB).
// dinv stays pre-scaled into tables (R9).
//
// ws (4B units): dinv[Np] rowptr[Np+4] counts[MAXBK*NB] bsum[128]
//   csr_src[E] tmpP[E] | h ushort[N*128 sliced 8x16] (reused as h2 8x8)
//   | h1 ushort[N*128 row-major]
// ---------------------------------------------------------------------------

typedef unsigned int uint;
typedef unsigned short ushort;
typedef __attribute__((ext_vector_type(8))) short bf16x8;
typedef __attribute__((ext_vector_type(8))) ushort u16x8;
typedef __attribute__((ext_vector_type(4))) float f32x4;

#define BSHIFT 8          // nodes per bucket = 256
#define MAXBK  512        // max buckets (N <= 131072)
#define NB     256        // hist/scatter blocks
#define CAP    8192       // LDS-staged edges per bucket (avg ~4096)

__device__ inline ushort f2bf(float f) {
    uint u = __float_as_uint(f);
    return (ushort)((u + 0x7fffu + ((u >> 16) & 1u)) >> 16);  // RNE
}
__device__ inline float bf_lo(uint u) { return __uint_as_float(u << 16); }
__device__ inline float bf_hi(uint u) { return __uint_as_float(u & 0xffff0000u); }

// ---- pass 1: per-block bucket histogram (LDS atomics only) ----
__global__ __launch_bounds__(256) void hist_kernel(const int* __restrict__ tgt,
                                                   int* __restrict__ counts,
                                                   int E, int chunk, int nbk) {
    __shared__ int hist[MAXBK];
    int t = threadIdx.x, b = blockIdx.x;
    for (int i = t; i < nbk; i += 256) hist[i] = 0;
    __syncthreads();
    int s = b * chunk, e = min(E, s + chunk);
    int i = s + t * 4;
    for (; i + 3 < e; i += 1024) {
        int4 tv = *(const int4*)&tgt[i];
        atomicAdd(&hist[tv.x >> BSHIFT], 1);
        atomicAdd(&hist[tv.y >> BSHIFT], 1);
        atomicAdd(&hist[tv.z >> BSHIFT], 1);
        atomicAdd(&hist[tv.w >> BSHIFT], 1);
    }
    if (i < e)
        for (int k = i; k < e; ++k) atomicAdd(&hist[tgt[k] >> BSHIFT], 1);
    __syncthreads();
    for (int i2 = t; i2 < nbk; i2 += 256) counts[i2 * NB + b] = hist[i2];
}

// ---- scan step 1: per-1024 partial sums of counts ----
__global__ __launch_bounds__(256) void scan_partial(const int* __restrict__ in,
                                                    int* __restrict__ bsum, int M) {
    int t = threadIdx.x, b = blockIdx.x;
    int base = b * 1024 + t * 4;
    int s = 0;
#pragma unroll
    for (int k = 0; k < 4; ++k) s += (base + k < M) ? in[base + k] : 0;
#pragma unroll
    for (int off = 32; off > 0; off >>= 1) s += __shfl_down(s, off, 64);
    __shared__ int ws[4];
    if ((t & 63) == 0) ws[t >> 6] = s;
    __syncthreads();
    if (t == 0) bsum[b] = ws[0] + ws[1] + ws[2] + ws[3];
}

// ---- scan step 2: exclusive scan of counts in place (bsum prefix fused) ----
__global__ __launch_bounds__(256) void scan_final_counts(int* __restrict__ counts,
                                                         const int* __restrict__ bsum,
                                                         int M) {
    int t = threadIdx.x, b = blockIdx.x;
    int lane = t & 63, wid = t >> 6;
    int p = 0;
    for (int i = t; i < b; i += 256) p += bsum[i];
#pragma unroll
    for (int off = 32; off > 0; off >>= 1) p += __shfl_down(p, off, 64);
    __shared__ int ps[4];
    if (lane == 0) ps[wid] = p;
    __syncthreads();
    int pre = ps[0] + ps[1] + ps[2] + ps[3];

    int base = b * 1024 + t * 4;
    int d[4];
#pragma unroll
    for (int k = 0; k < 4; ++k) d[k] = (base + k < M) ? counts[base + k] : 0;
    int tot = d[0] + d[1] + d[2] + d[3];
    int incl = tot;
#pragma unroll
    for (int off = 1; off < 64; off <<= 1) {
        int u = __shfl_up(incl, off, 64);
        if (lane >= off) incl += u;
    }
    __shared__ int wsum[4];
    if (lane == 63) wsum[wid] = incl;
    __syncthreads();
    int woff = 0;
    for (int w = 0; w < wid; ++w) woff += wsum[w];
    int run = incl - tot + woff + pre;
#pragma unroll
    for (int k = 0; k < 4; ++k) {
        if (base + k < M) counts[base + k] = run;
        run += d[k];
    }
}

// ---- pass 2: scatter edges into bucket-contiguous packed tmp ----
__global__ __launch_bounds__(256) void bucket_scatter(const int* __restrict__ src,
                                                      const int* __restrict__ tgt,
                                                      const int* __restrict__ offsets,
                                                      int* __restrict__ tmpP,
                                                      int E, int chunk, int nbk) {
    __shared__ int cur[MAXBK];
    int t = threadIdx.x, b = blockIdx.x;
    for (int i = t; i < nbk; i += 256) cur[i] = offsets[i * NB + b];
    __syncthreads();
    int s = b * chunk, e = min(E, s + chunk);
    int i = s + t * 4;
    for (; i + 3 < e; i += 1024) {
        int4 sv = *(const int4*)&src[i];
        int4 tv = *(const int4*)&tgt[i];
        int p0 = atomicAdd(&cur[tv.x >> BSHIFT], 1);
        tmpP[p0] = (sv.x << BSHIFT) | (tv.x & 255);
        int p1 = atomicAdd(&cur[tv.y >> BSHIFT], 1);
        tmpP[p1] = (sv.y << BSHIFT) | (tv.y & 255);
        int p2 = atomicAdd(&cur[tv.z >> BSHIFT], 1);
        tmpP[p2] = (sv.z << BSHIFT) | (tv.z & 255);
        int p3 = atomicAdd(&cur[tv.w >> BSHIFT], 1);
        tmpP[p3] = (sv.w << BSHIFT) | (tv.w & 255);
    }
    if (i < e) {
        for (int k = i; k < e; ++k) {
            int tg = tgt[k];
            int p = atomicAdd(&cur[tg >> BSHIFT], 1);
            tmpP[p] = (src[k] << BSHIFT) | (tg & 255);
        }
    }
}

// ---- pass 3 (fused): per-bucket deg count + scan + rowptr/dinv + csr fill ----
__global__ __launch_bounds__(256) void bucket_finish(const int* __restrict__ tmpP,
                                                     const int* __restrict__ offsets,
                                                     int* __restrict__ rowptr,
                                                     float* __restrict__ dinv,
                                                     int* __restrict__ csr_src,
                                                     int N, int E, int nbk) {
    __shared__ int stage[CAP];
    __shared__ int cnt[256];
    __shared__ int wsum[4];
    int t = threadIdx.x, b = blockIdx.x;
    cnt[t] = 0;
    __syncthreads();
    int s = offsets[b * NB];
    int e = (b + 1 < nbk) ? offsets[(b + 1) * NB] : E;
    int m = e - s;
    for (int i = t; i < m; i += 256) {
        int ed = tmpP[s + i];
        if (i < CAP) stage[i] = ed;
        atomicAdd(&cnt[ed & 255], 1);
    }
    __syncthreads();
    int lane = t & 63, wid = t >> 6;
    int d = cnt[t];
    int incl = d;
#pragma unroll
    for (int off = 1; off < 64; off <<= 1) {
        int u = __shfl_up(incl, off, 64);
        if (lane >= off) incl += u;
    }
    if (lane == 63) wsum[wid] = incl;
    __syncthreads();
    int woff = 0;
    for (int w = 0; w < wid; ++w) woff += wsum[w];
    int excl = s + incl - d + woff;
    int node = b * 256 + t;
    if (node < N) {
        rowptr[node] = excl;
        dinv[node] = rsqrtf((float)d + 1.0f);  // +1 self-loop
    }
    if (b == nbk - 1 && t == 255) rowptr[N] = E;
    cnt[t] = excl;  // reuse as cursor
    __syncthreads();
    for (int i = t; i < m; i += 256) {
        int ed = (i < CAP) ? stage[i] : tmpP[s + i];
        int p = atomicAdd(&cnt[ed & 255], 1);
        csr_src[p] = ed >> BSHIFT;
    }
}

// ---- MFMA GEMM: C(sliced bf16) = dinv[row] * (A[N,128] @ W[128,M]) ----
// Output layout: 8 column slices of SCOLS, slice s at C + s*N*SCOLS.
template <int M, int SCOLS, typename AT>
__global__ __launch_bounds__(256) void gemm_mfma(const AT* __restrict__ A,
                                                 const float* __restrict__ W,
                                                 const float* __restrict__ dinv,
                                                 ushort* __restrict__ C, int N) {
    constexpr int WTS = 136;           // padded row stride (bf16)
    __shared__ ushort WT[M * WTS];     // WT[n][k] = W[k][n]
    const int tid = threadIdx.x;
    for (int i = tid; i < 128 * (M / 4); i += 256) {
        int k = i / (M / 4);
        int n0 = (i % (M / 4)) * 4;
        float4 w = *(const float4*)&W[k * M + n0];
        WT[(n0 + 0) * WTS + k] = f2bf(w.x);
        WT[(n0 + 1) * WTS + k] = f2bf(w.y);
        WT[(n0 + 2) * WTS + k] = f2bf(w.z);
        WT[(n0 + 3) * WTS + k] = f2bf(w.w);
    }
    __syncthreads();

    const int wv = tid >> 6, lane = tid & 63;
    const int quad = lane >> 4, mrow = lane & 15;
    int arow_i = blockIdx.x * 64 + wv * 16 + mrow;
    if (arow_i >= N) arow_i = N - 1;   // clamp loads; stores guarded
    const AT* arow = &A[(size_t)arow_i * 128];

    f32x4 acc[M / 16];
#pragma unroll
    for (int t = 0; t < M / 16; ++t) acc[t] = (f32x4){0.f, 0.f, 0.f, 0.f};

#pragma unroll
    for (int ks = 0; ks < 4; ++ks) {
        const int k0 = ks * 32 + quad * 8;
        bf16x8 af;
        if constexpr (sizeof(AT) == 4) {
            float4 a0 = *(const float4*)&arow[k0];
            float4 a1 = *(const float4*)&arow[k0 + 4];
            af[0] = (short)f2bf(a0.x); af[1] = (short)f2bf(a0.y);
            af[2] = (short)f2bf(a0.z); af[3] = (short)f2bf(a0.w);
            af[4] = (short)f2bf(a1.x); af[5] = (short)f2bf(a1.y);
            af[6] = (short)f2bf(a1.z); af[7] = (short)f2bf(a1.w);
        } else {
            af = *(const bf16x8*)&arow[k0];
        }
#pragma unroll
        for (int t = 0; t < M / 16; ++t) {
            int n = t * 16 + mrow;
            bf16x8 bfr = *(const bf16x8*)&WT[n * WTS + k0];
            acc[t] = __builtin_amdgcn_mfma_f32_16x16x32_bf16(af, bfr, acc[t], 0, 0, 0);
        }
    }

    const int orow0 = blockIdx.x * 64 + wv * 16 + quad * 4;
#pragma unroll
    for (int r = 0; r < 4; ++r) {
        int orow = orow0 + r;
        if (orow < N) {
            float dv = dinv[orow];   // pre-scale row into the gather table
#pragma unroll
            for (int t = 0; t < M / 16; ++t) {
                int col = t * 16 + mrow;
                int slice = col / SCOLS, within = col % SCOLS;
                C[(size_t)slice * N * SCOLS + (size_t)orow * SCOLS + within] =
                    f2bf(dv * acc[t][r]);
            }
        }
    }
}

// ---- XCD-affine sliced pull gather.  slice = blockIdx&7 (round-robin XCD).
// COLS per slice; Q = COLS/8 lanes/row; G = 64/Q edge slots; 8 nodes/wave.
// out[v]_cols = dinv[v]*(sum h'[src] + h'[v]) + b   (tables pre-scaled)
template <int COLS, bool RELU, bool OUTBF, int OS>
__global__ __launch_bounds__(256) void gather_sliced(
    const ushort* __restrict__ hbase, const int* __restrict__ rowptr,
    const int* __restrict__ csr_src, const float* __restrict__ dinv,
    const float* __restrict__ bias, void* __restrict__ outv, int N) {
    constexpr int Q = COLS / 8;   // lanes per row (16B each)
    constexpr int G = 64 / Q;     // edge slots per wave
    const int slice = blockIdx.x & 7;
    const int group = blockIdx.x >> 3;
    const int wid = threadIdx.x >> 6, lane = threadIdx.x & 63;
    const int g = lane / Q, q = lane % Q;
    const int qoff = q * 8;
    const ushort* __restrict__ h = hbase + (size_t)slice * N * COLS;
    const float* bs = bias + slice * COLS;
    const int cbase = slice * COLS + qoff;

    for (int i = 0; i < 8; ++i) {
        int node = group * 32 + wid * 8 + i;
        if (node >= N) break;  // wave-uniform
        const int beg = rowptr[node], end = rowptr[node + 1];
        float acc[8] = {};
        for (int j = beg; j < end; j += G) {
            int e = j + g;
            bool v = e < end;
            int s = v ? csr_src[e] : node;
            float m = v ? 1.0f : 0.0f;
            uint4 hv = *(const uint4*)&h[(size_t)s * COLS + qoff];
            acc[0] += m * bf_lo(hv.x); acc[1] += m * bf_hi(hv.x);
            acc[2] += m * bf_lo(hv.y); acc[3] += m * bf_hi(hv.y);
            acc[4] += m * bf_lo(hv.z); acc[5] += m * bf_hi(hv.z);
            acc[6] += m * bf_lo(hv.w); acc[7] += m * bf_hi(hv.w);
        }
#pragma unroll
        for (int mk = Q; mk < 64; mk <<= 1)
#pragma unroll
            for (int k = 0; k < 8; ++k) acc[k] += __shfl_xor(acc[k], mk, 64);

        {   // self-loop: + h'[node]
            uint4 hv = *(const uint4*)&h[(size_t)node * COLS + qoff];
            acc[0] += bf_lo(hv.x); acc[1] += bf_hi(hv.x);
            acc[2] += bf_lo(hv.y); acc[3] += bf_hi(hv.y);
            acc[4] += bf_lo(hv.z); acc[5] += bf_hi(hv.z);
            acc[6] += bf_lo(hv.w); acc[7] += bf_hi(hv.w);
        }
        if (g == 0) {
            const float di = dinv[node];
            float4 b0 = *(const float4*)&bs[qoff];
            float4 b1 = *(const float4*)&bs[qoff + 4];
            float r[8] = {di * acc[0] + b0.x, di * acc[1] + b0.y,
                          di * acc[2] + b0.z, di * acc[3] + b0.w,
                          di * acc[4] + b1.x, di * acc[5] + b1.y,
                          di * acc[6] + b1.z, di * acc[7] + b1.w};
            if (RELU) {
#pragma unroll
                for (int k = 0; k < 8; ++k) r[k] = fmaxf(r[k], 0.0f);
            }
            if constexpr (OUTBF) {
                ushort* out = (ushort*)outv;
                u16x8 o;
#pragma unroll
                for (int k = 0; k < 8; ++k) o[k] = f2bf(r[k]);
                *(u16x8*)&out[(size_t)node * OS + cbase] = o;
            } else {
                float* out = (float*)outv;
                *(float4*)&out[(size_t)node * OS + cbase]     = make_float4(r[0], r[1], r[2], r[3]);
                *(float4*)&out[(size_t)node * OS + cbase + 4] = make_float4(r[4], r[5], r[6], r[7]);
            }
        }
    }
}

extern "C" void kernel_launch(void* const* d_in, const int* in_sizes, int n_in,
                              void* d_out, int out_size, void* d_ws, size_t ws_size,
                              hipStream_t stream) {
    const float* x  = (const float*)d_in[0];
    const int*   ei = (const int*)d_in[1];
    const float* W1 = (const float*)d_in[2];
    const float* b1 = (const float*)d_in[3];
    const float* W2 = (const float*)d_in[4];
    const float* b2 = (const float*)d_in[5];
    float* out = (float*)d_out;

    const int N = in_sizes[0] / 128;
    const int E = in_sizes[1] / 2;
    const int* src = ei;
    const int* tgt = ei + E;

    const int nbk   = (N + 255) >> BSHIFT;               // buckets
    const int chunk = (((E + NB - 1) / NB) + 3) & ~3;    // ×4 for int4 alignment
    const int Mc    = nbk * NB;                          // counts length

    float* ws = (float*)d_ws;
    const size_t Np = (size_t)((N + 3) & ~3);
    float*  dinv    = ws;                            // Np
    int*    rowptr  = (int*)(ws + Np);               // Np+4
    int*    counts  = rowptr + Np + 4;               // MAXBK*NB (scanned in place)
    int*    bsum    = counts + MAXBK * NB;           // 128
    int*    csr_src = bsum + 128;                    // E
    int*    tmpP    = csr_src + E;                   // E packed (src<<8)|(tgt&255)
    ushort* h       = (ushort*)(tmpP + E);           // N*128 bf16, sliced 8x16 (reused as h2 8x8)
    ushort* h1      = h + (size_t)N * 128;           // N*128 bf16 row-major
    ushort* h2      = h;

    const int nbc = (Mc + 1023) / 1024;
    const int ngrp = (N + 31) / 32;   // 32 nodes per gather block (4 waves x 8)

    // CSR build — no global atomics, no memsets (produces rowptr/dinv/csr_src)
    hist_kernel<<<NB, 256, 0, stream>>>(tgt, counts, E, chunk, nbk);
    scan_partial<<<nbc, 256, 0, stream>>>(counts, bsum, Mc);
    scan_final_counts<<<nbc, 256, 0, stream>>>(counts, bsum, Mc);
    bucket_scatter<<<NB, 256, 0, stream>>>(src, tgt, counts, tmpP, E, chunk, nbk);
    bucket_finish<<<nbk, 256, 0, stream>>>(tmpP, counts, rowptr, dinv, csr_src, N, E, nbk);

    // Layer 1: h' = dinv * (x@W1) in 8x16-col slices; XCD-affine gather -> h1
    gemm_mfma<128, 16, float><<<(N + 63) / 64, 256, 0, stream>>>(x, W1, dinv, h, N);
    gather_sliced<16, true, true, 128><<<ngrp * 8, 256, 0, stream>>>(
        h, rowptr, csr_src, dinv, b1, h1, N);

    // Layer 2: h2' = dinv * (h1@W2) in 8x8-col slices; XCD-affine gather -> out
    gemm_mfma<64, 8, ushort><<<(N + 63) / 64, 256, 0, stream>>>(h1, W2, dinv, h2, N);
    gather_sliced<8, false, false, 64><<<ngrp * 8, 256, 0, stream>>>(
        h2, rowptr, csr_src, dinv, b2, out, N);
}

// Round 11
// 424.765 us; speedup vs baseline: 2.1039x; 2.1039x over previous
//
#include <hip/hip_runtime.h>

// ---------------------------------------------------------------------------
// 2-layer GCN forward, pull-mode, bf16 tables, MFMA GEMMs.
//
// R11: XCD-affine sliced tables (R10: FETCH 271->34 MB, proven) + lane-per-
// node gather (fixes R10's 417us shuffle-reduction wall: 36M LDS-pipe ops).
// Each lane owns one node: walks its edge run serially, accumulates the
// full slice (16/8 cols) in registers.  No cross-lane reduction at all.
// Lanes hold consecutive nodes -> csr reads are contiguous per wave.
//
// ws (4B units): dinv[Np] rowptr[Np+4] counts[MAXBK*NB] bsum[128]
//   csr_src[E] tmpP[E] | h ushort[N*128 sliced 8x16] (reused as h2 8x8)
//   | h1 ushort[N*128 row-major]
// ---------------------------------------------------------------------------

typedef unsigned int uint;
typedef unsigned short ushort;
typedef __attribute__((ext_vector_type(8))) short bf16x8;
typedef __attribute__((ext_vector_type(8))) ushort u16x8;
typedef __attribute__((ext_vector_type(4))) float f32x4;

#define BSHIFT 8          // nodes per bucket = 256
#define MAXBK  512        // max buckets (N <= 131072)
#define NB     256        // hist/scatter blocks
#define CAP    8192       // LDS-staged edges per bucket (avg ~4096)

__device__ inline ushort f2bf(float f) {
    uint u = __float_as_uint(f);
    return (ushort)((u + 0x7fffu + ((u >> 16) & 1u)) >> 16);  // RNE
}
__device__ inline float bf_lo(uint u) { return __uint_as_float(u << 16); }
__device__ inline float bf_hi(uint u) { return __uint_as_float(u & 0xffff0000u); }

// ---- pass 1: per-block bucket histogram (LDS atomics only) ----
__global__ __launch_bounds__(256) void hist_kernel(const int* __restrict__ tgt,
                                                   int* __restrict__ counts,
                                                   int E, int chunk, int nbk) {
    __shared__ int hist[MAXBK];
    int t = threadIdx.x, b = blockIdx.x;
    for (int i = t; i < nbk; i += 256) hist[i] = 0;
    __syncthreads();
    int s = b * chunk, e = min(E, s + chunk);
    int i = s + t * 4;
    for (; i + 3 < e; i += 1024) {
        int4 tv = *(const int4*)&tgt[i];
        atomicAdd(&hist[tv.x >> BSHIFT], 1);
        atomicAdd(&hist[tv.y >> BSHIFT], 1);
        atomicAdd(&hist[tv.z >> BSHIFT], 1);
        atomicAdd(&hist[tv.w >> BSHIFT], 1);
    }
    if (i < e)
        for (int k = i; k < e; ++k) atomicAdd(&hist[tgt[k] >> BSHIFT], 1);
    __syncthreads();
    for (int i2 = t; i2 < nbk; i2 += 256) counts[i2 * NB + b] = hist[i2];
}

// ---- scan step 1: per-1024 partial sums of counts ----
__global__ __launch_bounds__(256) void scan_partial(const int* __restrict__ in,
                                                    int* __restrict__ bsum, int M) {
    int t = threadIdx.x, b = blockIdx.x;
    int base = b * 1024 + t * 4;
    int s = 0;
#pragma unroll
    for (int k = 0; k < 4; ++k) s += (base + k < M) ? in[base + k] : 0;
#pragma unroll
    for (int off = 32; off > 0; off >>= 1) s += __shfl_down(s, off, 64);
    __shared__ int ws[4];
    if ((t & 63) == 0) ws[t >> 6] = s;
    __syncthreads();
    if (t == 0) bsum[b] = ws[0] + ws[1] + ws[2] + ws[3];
}

// ---- scan step 2: exclusive scan of counts in place (bsum prefix fused) ----
__global__ __launch_bounds__(256) void scan_final_counts(int* __restrict__ counts,
                                                         const int* __restrict__ bsum,
                                                         int M) {
    int t = threadIdx.x, b = blockIdx.x;
    int lane = t & 63, wid = t >> 6;
    int p = 0;
    for (int i = t; i < b; i += 256) p += bsum[i];
#pragma unroll
    for (int off = 32; off > 0; off >>= 1) p += __shfl_down(p, off, 64);
    __shared__ int ps[4];
    if (lane == 0) ps[wid] = p;
    __syncthreads();
    int pre = ps[0] + ps[1] + ps[2] + ps[3];

    int base = b * 1024 + t * 4;
    int d[4];
#pragma unroll
    for (int k = 0; k < 4; ++k) d[k] = (base + k < M) ? counts[base + k] : 0;
    int tot = d[0] + d[1] + d[2] + d[3];
    int incl = tot;
#pragma unroll
    for (int off = 1; off < 64; off <<= 1) {
        int u = __shfl_up(incl, off, 64);
        if (lane >= off) incl += u;
    }
    __shared__ int wsum[4];
    if (lane == 63) wsum[wid] = incl;
    __syncthreads();
    int woff = 0;
    for (int w = 0; w < wid; ++w) woff += wsum[w];
    int run = incl - tot + woff + pre;
#pragma unroll
    for (int k = 0; k < 4; ++k) {
        if (base + k < M) counts[base + k] = run;
        run += d[k];
    }
}

// ---- pass 2: scatter edges into bucket-contiguous packed tmp ----
__global__ __launch_bounds__(256) void bucket_scatter(const int* __restrict__ src,
                                                      const int* __restrict__ tgt,
                                                      const int* __restrict__ offsets,
                                                      int* __restrict__ tmpP,
                                                      int E, int chunk, int nbk) {
    __shared__ int cur[MAXBK];
    int t = threadIdx.x, b = blockIdx.x;
    for (int i = t; i < nbk; i += 256) cur[i] = offsets[i * NB + b];
    __syncthreads();
    int s = b * chunk, e = min(E, s + chunk);
    int i = s + t * 4;
    for (; i + 3 < e; i += 1024) {
        int4 sv = *(const int4*)&src[i];
        int4 tv = *(const int4*)&tgt[i];
        int p0 = atomicAdd(&cur[tv.x >> BSHIFT], 1);
        tmpP[p0] = (sv.x << BSHIFT) | (tv.x & 255);
        int p1 = atomicAdd(&cur[tv.y >> BSHIFT], 1);
        tmpP[p1] = (sv.y << BSHIFT) | (tv.y & 255);
        int p2 = atomicAdd(&cur[tv.z >> BSHIFT], 1);
        tmpP[p2] = (sv.z << BSHIFT) | (tv.z & 255);
        int p3 = atomicAdd(&cur[tv.w >> BSHIFT], 1);
        tmpP[p3] = (sv.w << BSHIFT) | (tv.w & 255);
    }
    if (i < e) {
        for (int k = i; k < e; ++k) {
            int tg = tgt[k];
            int p = atomicAdd(&cur[tg >> BSHIFT], 1);
            tmpP[p] = (src[k] << BSHIFT) | (tg & 255);
        }
    }
}

// ---- pass 3 (fused): per-bucket deg count + scan + rowptr/dinv + csr fill ----
__global__ __launch_bounds__(256) void bucket_finish(const int* __restrict__ tmpP,
                                                     const int* __restrict__ offsets,
                                                     int* __restrict__ rowptr,
                                                     float* __restrict__ dinv,
                                                     int* __restrict__ csr_src,
                                                     int N, int E, int nbk) {
    __shared__ int stage[CAP];
    __shared__ int cnt[256];
    __shared__ int wsum[4];
    int t = threadIdx.x, b = blockIdx.x;
    cnt[t] = 0;
    __syncthreads();
    int s = offsets[b * NB];
    int e = (b + 1 < nbk) ? offsets[(b + 1) * NB] : E;
    int m = e - s;
    for (int i = t; i < m; i += 256) {
        int ed = tmpP[s + i];
        if (i < CAP) stage[i] = ed;
        atomicAdd(&cnt[ed & 255], 1);
    }
    __syncthreads();
    int lane = t & 63, wid = t >> 6;
    int d = cnt[t];
    int incl = d;
#pragma unroll
    for (int off = 1; off < 64; off <<= 1) {
        int u = __shfl_up(incl, off, 64);
        if (lane >= off) incl += u;
    }
    if (lane == 63) wsum[wid] = incl;
    __syncthreads();
    int woff = 0;
    for (int w = 0; w < wid; ++w) woff += wsum[w];
    int excl = s + incl - d + woff;
    int node = b * 256 + t;
    if (node < N) {
        rowptr[node] = excl;
        dinv[node] = rsqrtf((float)d + 1.0f);  // +1 self-loop
    }
    if (b == nbk - 1 && t == 255) rowptr[N] = E;
    cnt[t] = excl;  // reuse as cursor
    __syncthreads();
    for (int i = t; i < m; i += 256) {
        int ed = (i < CAP) ? stage[i] : tmpP[s + i];
        int p = atomicAdd(&cnt[ed & 255], 1);
        csr_src[p] = ed >> BSHIFT;
    }
}

// ---- MFMA GEMM: C(sliced bf16) = dinv[row] * (A[N,128] @ W[128,M]) ----
// Output layout: 8 column slices of SCOLS, slice s at C + s*N*SCOLS.
template <int M, int SCOLS, typename AT>
__global__ __launch_bounds__(256) void gemm_mfma(const AT* __restrict__ A,
                                                 const float* __restrict__ W,
                                                 const float* __restrict__ dinv,
                                                 ushort* __restrict__ C, int N) {
    constexpr int WTS = 136;           // padded row stride (bf16)
    __shared__ ushort WT[M * WTS];     // WT[n][k] = W[k][n]
    const int tid = threadIdx.x;
    for (int i = tid; i < 128 * (M / 4); i += 256) {
        int k = i / (M / 4);
        int n0 = (i % (M / 4)) * 4;
        float4 w = *(const float4*)&W[k * M + n0];
        WT[(n0 + 0) * WTS + k] = f2bf(w.x);
        WT[(n0 + 1) * WTS + k] = f2bf(w.y);
        WT[(n0 + 2) * WTS + k] = f2bf(w.z);
        WT[(n0 + 3) * WTS + k] = f2bf(w.w);
    }
    __syncthreads();

    const int wv = tid >> 6, lane = tid & 63;
    const int quad = lane >> 4, mrow = lane & 15;
    int arow_i = blockIdx.x * 64 + wv * 16 + mrow;
    if (arow_i >= N) arow_i = N - 1;   // clamp loads; stores guarded
    const AT* arow = &A[(size_t)arow_i * 128];

    f32x4 acc[M / 16];
#pragma unroll
    for (int t = 0; t < M / 16; ++t) acc[t] = (f32x4){0.f, 0.f, 0.f, 0.f};

#pragma unroll
    for (int ks = 0; ks < 4; ++ks) {
        const int k0 = ks * 32 + quad * 8;
        bf16x8 af;
        if constexpr (sizeof(AT) == 4) {
            float4 a0 = *(const float4*)&arow[k0];
            float4 a1 = *(const float4*)&arow[k0 + 4];
            af[0] = (short)f2bf(a0.x); af[1] = (short)f2bf(a0.y);
            af[2] = (short)f2bf(a0.z); af[3] = (short)f2bf(a0.w);
            af[4] = (short)f2bf(a1.x); af[5] = (short)f2bf(a1.y);
            af[6] = (short)f2bf(a1.z); af[7] = (short)f2bf(a1.w);
        } else {
            af = *(const bf16x8*)&arow[k0];
        }
#pragma unroll
        for (int t = 0; t < M / 16; ++t) {
            int n = t * 16 + mrow;
            bf16x8 bfr = *(const bf16x8*)&WT[n * WTS + k0];
            acc[t] = __builtin_amdgcn_mfma_f32_16x16x32_bf16(af, bfr, acc[t], 0, 0, 0);
        }
    }

    const int orow0 = blockIdx.x * 64 + wv * 16 + quad * 4;
#pragma unroll
    for (int r = 0; r < 4; ++r) {
        int orow = orow0 + r;
        if (orow < N) {
            float dv = dinv[orow];   // pre-scale row into the gather table
#pragma unroll
            for (int t = 0; t < M / 16; ++t) {
                int col = t * 16 + mrow;
                int slice = col / SCOLS, within = col % SCOLS;
                C[(size_t)slice * N * SCOLS + (size_t)orow * SCOLS + within] =
                    f2bf(dv * acc[t][r]);
            }
        }
    }
}

// ---- lane-per-node XCD-affine sliced gather.  slice = blockIdx&7.
// Each lane owns one node: serial edge walk, full COLS accumulated in
// registers, no cross-lane ops.  Lanes hold consecutive nodes -> csr reads
// contiguous per wave.  Tables pre-scaled by dinv (R9).
template <int COLS, bool RELU, bool OUTBF, int OS>
__global__ __launch_bounds__(256) void gather_lane(
    const ushort* __restrict__ hbase, const int* __restrict__ rowptr,
    const int* __restrict__ csr_src, const float* __restrict__ dinv,
    const float* __restrict__ bias, void* __restrict__ outv, int N) {
    constexpr int SEG = COLS / 8;      // uint4 segments per slice row
    const int slice = blockIdx.x & 7;
    const int group = blockIdx.x >> 3;
    const int node = group * 256 + threadIdx.x;
    if (node >= N) return;
    const ushort* __restrict__ h = hbase + (size_t)slice * N * COLS;

    float acc[COLS];
    {   // self-loop init: acc = h'[node]
#pragma unroll
        for (int sg = 0; sg < SEG; ++sg) {
            uint4 hv = *(const uint4*)&h[(size_t)node * COLS + sg * 8];
            acc[sg * 8 + 0] = bf_lo(hv.x); acc[sg * 8 + 1] = bf_hi(hv.x);
            acc[sg * 8 + 2] = bf_lo(hv.y); acc[sg * 8 + 3] = bf_hi(hv.y);
            acc[sg * 8 + 4] = bf_lo(hv.z); acc[sg * 8 + 5] = bf_hi(hv.z);
            acc[sg * 8 + 6] = bf_lo(hv.w); acc[sg * 8 + 7] = bf_hi(hv.w);
        }
    }
    const int beg = rowptr[node], end = rowptr[node + 1];
    int j = beg;
    for (; j + 2 <= end; j += 2) {     // 2 edges in flight per lane
        int s0 = csr_src[j], s1 = csr_src[j + 1];
#pragma unroll
        for (int sg = 0; sg < SEG; ++sg) {
            uint4 a = *(const uint4*)&h[(size_t)s0 * COLS + sg * 8];
            uint4 b = *(const uint4*)&h[(size_t)s1 * COLS + sg * 8];
            acc[sg * 8 + 0] += bf_lo(a.x) + bf_lo(b.x);
            acc[sg * 8 + 1] += bf_hi(a.x) + bf_hi(b.x);
            acc[sg * 8 + 2] += bf_lo(a.y) + bf_lo(b.y);
            acc[sg * 8 + 3] += bf_hi(a.y) + bf_hi(b.y);
            acc[sg * 8 + 4] += bf_lo(a.z) + bf_lo(b.z);
            acc[sg * 8 + 5] += bf_hi(a.z) + bf_hi(b.z);
            acc[sg * 8 + 6] += bf_lo(a.w) + bf_lo(b.w);
            acc[sg * 8 + 7] += bf_hi(a.w) + bf_hi(b.w);
        }
    }
    if (j < end) {
        int s0 = csr_src[j];
#pragma unroll
        for (int sg = 0; sg < SEG; ++sg) {
            uint4 a = *(const uint4*)&h[(size_t)s0 * COLS + sg * 8];
            acc[sg * 8 + 0] += bf_lo(a.x); acc[sg * 8 + 1] += bf_hi(a.x);
            acc[sg * 8 + 2] += bf_lo(a.y); acc[sg * 8 + 3] += bf_hi(a.y);
            acc[sg * 8 + 4] += bf_lo(a.z); acc[sg * 8 + 5] += bf_hi(a.z);
            acc[sg * 8 + 6] += bf_lo(a.w); acc[sg * 8 + 7] += bf_hi(a.w);
        }
    }

    const float di = dinv[node];
    const float* bs = bias + slice * COLS;
    float r[COLS];
#pragma unroll
    for (int k = 0; k < COLS; ++k) {
        r[k] = di * acc[k] + bs[k];
        if (RELU) r[k] = fmaxf(r[k], 0.0f);
    }
    const int cbase = slice * COLS;
    if constexpr (OUTBF) {
        ushort* out = (ushort*)outv;
#pragma unroll
        for (int sg = 0; sg < SEG; ++sg) {
            u16x8 o;
#pragma unroll
            for (int k = 0; k < 8; ++k) o[k] = f2bf(r[sg * 8 + k]);
            *(u16x8*)&out[(size_t)node * OS + cbase + sg * 8] = o;
        }
    } else {
        float* out = (float*)outv;
#pragma unroll
        for (int sg = 0; sg < SEG; ++sg) {
            *(float4*)&out[(size_t)node * OS + cbase + sg * 8] =
                make_float4(r[sg * 8 + 0], r[sg * 8 + 1], r[sg * 8 + 2], r[sg * 8 + 3]);
            *(float4*)&out[(size_t)node * OS + cbase + sg * 8 + 4] =
                make_float4(r[sg * 8 + 4], r[sg * 8 + 5], r[sg * 8 + 6], r[sg * 8 + 7]);
        }
    }
}

extern "C" void kernel_launch(void* const* d_in, const int* in_sizes, int n_in,
                              void* d_out, int out_size, void* d_ws, size_t ws_size,
                              hipStream_t stream) {
    const float* x  = (const float*)d_in[0];
    const int*   ei = (const int*)d_in[1];
    const float* W1 = (const float*)d_in[2];
    const float* b1 = (const float*)d_in[3];
    const float* W2 = (const float*)d_in[4];
    const float* b2 = (const float*)d_in[5];
    float* out = (float*)d_out;

    const int N = in_sizes[0] / 128;
    const int E = in_sizes[1] / 2;
    const int* src = ei;
    const int* tgt = ei + E;

    const int nbk   = (N + 255) >> BSHIFT;               // buckets
    const int chunk = (((E + NB - 1) / NB) + 3) & ~3;    // ×4 for int4 alignment
    const int Mc    = nbk * NB;                          // counts length

    float* ws = (float*)d_ws;
    const size_t Np = (size_t)((N + 3) & ~3);
    float*  dinv    = ws;                            // Np
    int*    rowptr  = (int*)(ws + Np);               // Np+4
    int*    counts  = rowptr + Np + 4;               // MAXBK*NB (scanned in place)
    int*    bsum    = counts + MAXBK * NB;           // 128
    int*    csr_src = bsum + 128;                    // E
    int*    tmpP    = csr_src + E;                   // E packed (src<<8)|(tgt&255)
    ushort* h       = (ushort*)(tmpP + E);           // N*128 bf16, sliced 8x16 (reused as h2 8x8)
    ushort* h1      = h + (size_t)N * 128;           // N*128 bf16 row-major
    ushort* h2      = h;

    const int nbc = (Mc + 1023) / 1024;
    const int ngrp = (N + 255) / 256;   // 256 nodes per gather block (1/lane)

    // CSR build — no global atomics, no memsets (produces rowptr/dinv/csr_src)
    hist_kernel<<<NB, 256, 0, stream>>>(tgt, counts, E, chunk, nbk);
    scan_partial<<<nbc, 256, 0, stream>>>(counts, bsum, Mc);
    scan_final_counts<<<nbc, 256, 0, stream>>>(counts, bsum, Mc);
    bucket_scatter<<<NB, 256, 0, stream>>>(src, tgt, counts, tmpP, E, chunk, nbk);
    bucket_finish<<<nbk, 256, 0, stream>>>(tmpP, counts, rowptr, dinv, csr_src, N, E, nbk);

    // Layer 1: h' = dinv * (x@W1) in 8x16-col slices; XCD-affine gather -> h1
    gemm_mfma<128, 16, float><<<(N + 63) / 64, 256, 0, stream>>>(x, W1, dinv, h, N);
    gather_lane<16, true, true, 128><<<ngrp * 8, 256, 0, stream>>>(
        h, rowptr, csr_src, dinv, b1, h1, N);

    // Layer 2: h2' = dinv * (h1@W2) in 8x8-col slices; XCD-affine gather -> out
    gemm_mfma<64, 8, ushort><<<(N + 63) / 64, 256, 0, stream>>>(h1, W2, dinv, h2, N);
    gather_lane<8, false, false, 64><<<ngrp * 8, 256, 0, stream>>>(
        h2, rowptr, csr_src, dinv, b2, out, N);
}